// Round 1
// baseline (389.170 us; speedup 1.0000x reference)
//
#include <hip/hip_runtime.h>

// Problem constants (B,C,H,W) = (8,32,512,512), K=9
#define HH 512
#define WW 512
#define SEGS 8
#define LOG2SEGS 3
#define SEGROWS 64    // HH / SEGS  (was 32: halo over-read 25% -> 12.5%)
#define CG 128        // float4 column-groups per row (WW/4)
#define NBLOCKS 1024  // 256 planes * SEGS * CG / 256 threads

__device__ __forceinline__ int imax(int a, int b) { return a > b ? a : b; }
__device__ __forceinline__ int imin(int a, int b) { return a < b ? a : b; }

// out = (1/8) * [ sum (81 + ch(h)*cw(w)) * x^2  -  2 * sum RowBox9(x) * ColBox9(x) ]
// Branch-free streaming: all loads unconditional (clamped addresses), zero-padding
// via 0/1 mask multiplies so loads pipeline across unrolled iterations.

// Stream one image row through the sliding-window rings.
#define STREAM_ROW(rr)                                                         \
    {                                                                          \
        const int r   = (rr);                                                  \
        const int rc_ = imin(imax(r, 0), HH - 1);                              \
        const float m = ((unsigned)r < (unsigned)HH) ? 1.f : 0.f;              \
        const char* rowb = (const char*)(base + (ptrdiff_t)rc_ * WW);          \
        float4 lcr = *(const float4*)(rowb + offL);                            \
        float4 ccr = *(const float4*)(rowb + offC);                            \
        float4 rcr = *(const float4*)(rowb + offR);                            \
        const float a = mL * m, b = mR * m;                                    \
        float4 lc = make_float4(lcr.x * a, lcr.y * a, lcr.z * a, lcr.w * a);   \
        float4 cc = make_float4(ccr.x * m, ccr.y * m, ccr.z * m, ccr.w * m);   \
        float4 rc = make_float4(rcr.x * b, rcr.y * b, rcr.z * b, rcr.w * b);   \
        float R0 = ((lc.x + lc.y) + (lc.z + lc.w)) +                           \
                   ((cc.x + cc.y) + (cc.z + cc.w)) + rc.x;                     \
        float R1 = R0 - lc.x + rc.y;                                           \
        float R2 = R1 - lc.y + rc.z;                                           \
        float R3 = R2 - lc.z + rc.w;                                           \
        float4 Rn = make_float4(R0, R1, R2, R3);                               \
        V.x += cc.x - x0.x; V.y += cc.y - x0.y;                                \
        V.z += cc.z - x0.z; V.w += cc.w - x0.w;                                \
        x0 = x1; x1 = x2; x2 = x3; x3 = x4; x4 = x5;                           \
        x5 = x6; x6 = x7; x7 = x8; x8 = cc;                                    \
        q0 = q1; q1 = q2; q2 = q3; q3 = q4; q4 = Rn;                           \
    }
// after STREAM_ROW(r): x0..x8 = x(r-8..r), center x4 = x(r-4), q0 = R(r-4),
//                      V = sum x(r-8..r)

__global__ __launch_bounds__(256, 4) void scc_kernel(const float* __restrict__ img,
                                                     float* __restrict__ out) {
    // XCD-aware bijective swizzle (NBLOCKS % 8 == 0): hardware round-robins
    // consecutive blockIdx.x across the 8 XCDs; remap so each XCD owns a
    // contiguous span of work-chunks -> a plane's 4 chunks (which share 8-row
    // halos; plane = 1 MiB << 4 MiB L2) stay in one XCD's L2, temporally close.
    const int swz   = (blockIdx.x & 7) * (NBLOCKS / 8) + (blockIdx.x >> 3);
    const int tid   = swz * 256 + (int)threadIdx.x;
    const int g     = tid & (CG - 1);      // column group: cols [4g, 4g+3]
    const int rest  = tid >> 7;
    const int seg   = rest & (SEGS - 1);
    const int plane = rest >> LOG2SEGS;

    const float* base = img + (size_t)plane * (HH * WW);
    const int r0 = seg * SEGROWS;

    // per-column border weight cw(w) = #valid horizontal window positions
    float4 cw;
    {
        int w0 = 4 * g;
        cw.x = (float)(9 - imax(0, 4 - (w0 + 0)) - imax(0, (w0 + 0) - (WW - 5)));
        cw.y = (float)(9 - imax(0, 4 - (w0 + 1)) - imax(0, (w0 + 1) - (WW - 5)));
        cw.z = (float)(9 - imax(0, 4 - (w0 + 2)) - imax(0, (w0 + 2) - (WW - 5)));
        cw.w = (float)(9 - imax(0, 4 - (w0 + 3)) - imax(0, (w0 + 3) - (WW - 5)));
    }

    // clamped neighbor offsets (bytes) + 0/1 edge masks, computed once
    const int offL = imax(g - 1, 0) * 16;
    const int offC = g * 16;
    const int offR = imin(g + 1, CG - 1) * 16;
    const float mL = (g > 0) ? 1.f : 0.f;
    const float mR = (g < CG - 1) ? 1.f : 0.f;

    const float4 z4 = make_float4(0.f, 0.f, 0.f, 0.f);
    // x-ring: x0..x8 = x(r-9 .. r-1) before the shift of streamed row r
    float4 x0 = z4, x1 = z4, x2 = z4, x3 = z4, x4 = z4,
           x5 = z4, x6 = z4, x7 = z4, x8 = z4;
    // R-ring: q0..q4 = R(r-5 .. r-1) before shift
    float4 q0 = z4, q1 = z4, q2 = z4, q3 = z4, q4 = z4;
    float4 V = z4;             // after update: sum x(r-8 .. r)
    float accW = 0.f, accRV = 0.f;

    // warm-up: fill rings with rows r0-4 .. r0+3 (no accumulation, branch-free)
#pragma unroll
    for (int i = 0; i < 8; ++i) {
        STREAM_ROW(r0 - 4 + i)
    }

    // main: stream rows r0+4 .. r0+SEGROWS+3, accumulating at h = r-4
#pragma unroll 8
    for (int i = 8; i < SEGROWS + 8; ++i) {
        STREAM_ROW(r0 - 4 + i)
        const int h = r0 + i - 8;          // output row = r - 4
        const float chf = (float)(9 - imax(0, 4 - h) - imax(0, h - (HH - 5)));
        float w0 = fmaf(chf, cw.x, 81.f);
        float w1 = fmaf(chf, cw.y, 81.f);
        float w2 = fmaf(chf, cw.z, 81.f);
        float w3 = fmaf(chf, cw.w, 81.f);
        accW = fmaf(w0 * x4.x, x4.x, accW);
        accW = fmaf(w1 * x4.y, x4.y, accW);
        accW = fmaf(w2 * x4.z, x4.z, accW);
        accW = fmaf(w3 * x4.w, x4.w, accW);
        accRV = fmaf(q0.x, V.x, accRV);
        accRV = fmaf(q0.y, V.y, accRV);
        accRV = fmaf(q0.z, V.z, accRV);
        accRV = fmaf(q0.w, V.w, accRV);
    }

    float acc = accW - 2.f * accRV;

    // reduce: wave64 shuffle -> LDS -> one atomic per block
#pragma unroll
    for (int off = 32; off > 0; off >>= 1)
        acc += __shfl_xor(acc, off, 64);
    __shared__ float wsum[4];
    const int lane = threadIdx.x & 63;
    const int wv   = threadIdx.x >> 6;
    if (lane == 0) wsum[wv] = acc;
    __syncthreads();
    if (threadIdx.x == 0) {
        float s = (wsum[0] + wsum[1]) + (wsum[2] + wsum[3]);
        atomicAdd(out, 0.125f * s);  // mean over batch (B = 8)
    }
}

extern "C" void kernel_launch(void* const* d_in, const int* in_sizes, int n_in,
                              void* d_out, int out_size, void* d_ws, size_t ws_size,
                              hipStream_t stream) {
    const float* img = (const float*)d_in[0];
    float* out = (float*)d_out;
    hipMemsetAsync(out, 0, sizeof(float), stream);  // d_out is poisoned 0xAA
    // 262144 work items: 256 planes x 8 row-segments x 128 column-groups
    scc_kernel<<<dim3(NBLOCKS), dim3(256), 0, stream>>>(img, out);
}

// Round 2
// 367.316 us; speedup vs baseline: 1.0595x; 1.0595x over previous
//
#include <hip/hip_runtime.h>

// Problem constants (B,C,H,W) = (8,32,512,512), K=9
#define HH 512
#define WW 512
#define SEGS 16
#define SEGROWS 32   // HH / SEGS
#define CG 128       // float4 column-groups per row (WW/4)
#define NBLOCKS 2048 // 256 planes * 16 segments * 128 col-groups / 256 threads

__device__ __forceinline__ int imax(int a, int b) { return a > b ? a : b; }
__device__ __forceinline__ int imin(int a, int b) { return a < b ? a : b; }

// out = (1/8) * [ sum (81 + ch(h)*cw(w)) * x^2  -  2 * sum RowBox9(x) * ColBox9(x) ]
// Branch-free: all loads unconditional (clamped addresses), zero-padding done
// with 0/1 float mask multiplies so loads pipeline across unrolled iterations.
__global__ __launch_bounds__(256, 4) void scc_kernel(const float* __restrict__ img,
                                                     float* __restrict__ out) {
    // XCD-aware bijective swizzle (NBLOCKS % 8 == 0). Block B covers two
    // adjacent row-segments of one plane; the halo boundary with block B+1 is
    // re-read by both. Default dispatch round-robins B and B+1 onto different
    // XCDs (private, non-coherent L2s) -> halo re-reads go to HBM/L3. Remap so
    // each XCD owns a contiguous span of 256 blocks (= 32 planes): neighbor
    // blocks share one XCD's L2, temporally adjacent -> halo becomes L2 hit.
    const int swz   = (blockIdx.x & 7) * (NBLOCKS / 8) + (blockIdx.x >> 3);
    const int tid   = swz * 256 + (int)threadIdx.x;
    const int g     = tid & (CG - 1);      // column group: cols [4g, 4g+3]
    const int rest  = tid >> 7;
    const int seg   = rest & (SEGS - 1);
    const int plane = rest >> 4;

    const float* base = img + (size_t)plane * (HH * WW);
    const int r0 = seg * SEGROWS;

    // per-column border weight cw(w) = #valid horizontal window positions
    float4 cw;
    {
        int w0 = 4 * g;
        cw.x = (float)(9 - imax(0, 4 - (w0 + 0)) - imax(0, (w0 + 0) - (WW - 5)));
        cw.y = (float)(9 - imax(0, 4 - (w0 + 1)) - imax(0, (w0 + 1) - (WW - 5)));
        cw.z = (float)(9 - imax(0, 4 - (w0 + 2)) - imax(0, (w0 + 2) - (WW - 5)));
        cw.w = (float)(9 - imax(0, 4 - (w0 + 3)) - imax(0, (w0 + 3) - (WW - 5)));
    }

    // clamped neighbor offsets (bytes) + 0/1 edge masks, computed once
    const int offL = imax(g - 1, 0) * 16;
    const int offC = g * 16;
    const int offR = imin(g + 1, CG - 1) * 16;
    const float mL = (g > 0) ? 1.f : 0.f;
    const float mR = (g < CG - 1) ? 1.f : 0.f;

    const float4 z4 = make_float4(0.f, 0.f, 0.f, 0.f);
    // x-ring: x0..x8 = x(r-9 .. r-1) before the shift of streamed row r
    float4 x0 = z4, x1 = z4, x2 = z4, x3 = z4, x4 = z4,
           x5 = z4, x6 = z4, x7 = z4, x8 = z4;
    // R-ring: q0..q4 = R(r-5 .. r-1) before shift
    float4 q0 = z4, q1 = z4, q2 = z4, q3 = z4, q4 = z4;
    float4 V = z4;             // after update: sum x(r-8 .. r)
    float accW = 0.f, accRV = 0.f;

#pragma unroll 8
    for (int i = 0; i < SEGROWS + 8; ++i) {
        const int r  = r0 - 4 + i;                   // streamed row (may be OOB)
        const int rc_ = imin(imax(r, 0), HH - 1);    // clamped (uniform, scalar)
        const float m = ((unsigned)r < (unsigned)HH) ? 1.f : 0.f;  // uniform 0/1
        const char* rowb = (const char*)(base + (ptrdiff_t)rc_ * WW);

        float4 lcr = *(const float4*)(rowb + offL);  // unconditional loads
        float4 ccr = *(const float4*)(rowb + offC);
        float4 rcr = *(const float4*)(rowb + offR);

        const float a = mL * m, b = mR * m;
        float4 lc = make_float4(lcr.x * a, lcr.y * a, lcr.z * a, lcr.w * a);
        float4 cc = make_float4(ccr.x * m, ccr.y * m, ccr.z * m, ccr.w * m);
        float4 rc = make_float4(rcr.x * b, rcr.y * b, rcr.z * b, rcr.w * b);

        // sliding horizontal 9-sums for the 4 owned columns
        float R0 = ((lc.x + lc.y) + (lc.z + lc.w)) + ((cc.x + cc.y) + (cc.z + cc.w)) + rc.x;
        float R1 = R0 - lc.x + rc.y;
        float R2 = R1 - lc.y + rc.z;
        float R3 = R2 - lc.z + rc.w;
        float4 Rn = make_float4(R0, R1, R2, R3);

        // running vertical 9-sum: V = sum x(r-8..r)
        V.x += cc.x - x0.x;  V.y += cc.y - x0.y;
        V.z += cc.z - x0.z;  V.w += cc.w - x0.w;

        // shift rings (renamed away by unrolling)
        x0 = x1; x1 = x2; x2 = x3; x3 = x4; x4 = x5;
        x5 = x6; x6 = x7; x7 = x8; x8 = cc;
        q0 = q1; q1 = q2; q2 = q3; q3 = q4; q4 = Rn;
        // now x0..x8 = x(r-8..r) -> center x = x4 = x(r-4); q0 = R(r-4)

        if (i >= 8) {   // constant-folds per unrolled body
            const int h = r - 4;
            const float chf = (float)(9 - imax(0, 4 - h) - imax(0, h - (HH - 5)));
            float w0 = fmaf(chf, cw.x, 81.f);
            float w1 = fmaf(chf, cw.y, 81.f);
            float w2 = fmaf(chf, cw.z, 81.f);
            float w3 = fmaf(chf, cw.w, 81.f);
            accW = fmaf(w0 * x4.x, x4.x, accW);
            accW = fmaf(w1 * x4.y, x4.y, accW);
            accW = fmaf(w2 * x4.z, x4.z, accW);
            accW = fmaf(w3 * x4.w, x4.w, accW);
            accRV = fmaf(q0.x, V.x, accRV);
            accRV = fmaf(q0.y, V.y, accRV);
            accRV = fmaf(q0.z, V.z, accRV);
            accRV = fmaf(q0.w, V.w, accRV);
        }
    }

    float acc = accW - 2.f * accRV;

    // reduce: wave64 shuffle -> LDS -> one atomic per block
#pragma unroll
    for (int off = 32; off > 0; off >>= 1)
        acc += __shfl_xor(acc, off, 64);
    __shared__ float wsum[4];
    const int lane = threadIdx.x & 63;
    const int wv   = threadIdx.x >> 6;
    if (lane == 0) wsum[wv] = acc;
    __syncthreads();
    if (threadIdx.x == 0) {
        float s = (wsum[0] + wsum[1]) + (wsum[2] + wsum[3]);
        atomicAdd(out, 0.125f * s);  // mean over batch (B = 8)
    }
}

extern "C" void kernel_launch(void* const* d_in, const int* in_sizes, int n_in,
                              void* d_out, int out_size, void* d_ws, size_t ws_size,
                              hipStream_t stream) {
    const float* img = (const float*)d_in[0];
    float* out = (float*)d_out;
    hipMemsetAsync(out, 0, sizeof(float), stream);  // d_out is poisoned 0xAA
    // 524288 work items: 256 planes x 16 row-segments x 128 column-groups
    scc_kernel<<<dim3(NBLOCKS), dim3(256), 0, stream>>>(img, out);
}